// Round 11
// baseline (75.168 us; speedup 1.0000x reference)
//
#include <hip/hip_runtime.h>

#define D 128
#define EPS 1e-3f

typedef short short8v __attribute__((ext_vector_type(8)));
typedef float f32x4  __attribute__((ext_vector_type(4)));
typedef unsigned short u16;
typedef u16 u16x4 __attribute__((ext_vector_type(4)));

// ws layout: [0,32K) U frags [wc(8)][s(4)][lane(64)]x8 bf16 ; [32K,64K) L frags ; [64K,+512) logdiag f32[128]
#define U_OFF 0
#define L_OFF (32*1024)
#define LD_OFF (64*1024)

__device__ __forceinline__ float softplus_f(float x) {
    return (x > 20.f) ? x : log1pf(expf(x));
}
__device__ __forceinline__ u16 f2bf(float f) {   // round-to-nearest-even f32->bf16
    unsigned u = __float_as_uint(f);
    unsigned r = (u + 0x7FFFu + ((u >> 16) & 1u)) >> 16;
    return (u16)r;
}

// Densify U^T / L^T into per-wave MFMA B-fragment order (bf16), + logdiag table.
// B-frag for 16x16x32: lane l holds B[k][col]: col = l&15, k = s*32 + (l>>4)*8 + e.
// One short8v per thread (16 blocks x 256 threads = 4096 threads = 2 matrices x 2048 frags).
__global__ __launch_bounds__(256)
void lu_setup_kernel(const float* __restrict__ low_e,
                     const float* __restrict__ up_e,
                     const float* __restrict__ ud,
                     char* __restrict__ ws)
{
    const int tid  = blockIdx.x * 256 + threadIdx.x;   // 0..4095
    const int mat  = tid >> 11;                        // 0 = U, 1 = L
    const int fidx = tid & 2047;                       // (wc*4+s)*64 + l
    const int l    = fidx & 63;
    const int s    = (fidx >> 6) & 3;
    const int wc   = fidx >> 8;
    const int i    = wc * 16 + (l & 15);               // matrix row of U/L (= output col)
    const int k0   = s * 32 + (l >> 4) * 8;

    short8v v8;
    #pragma unroll
    for (int e = 0; e < 8; ++e) {
        const int j = k0 + e;
        float f;
        if (mat == 0) {   // U: upper triangle + diag
            f = (j > i) ? up_e[i * 127 - (i * (i - 1)) / 2 + (j - i - 1)]
              : (j < i) ? 0.f
                        : softplus_f(ud[i]) + EPS;
        } else {          // L: lower triangle + unit diag
            f = (j < i) ? low_e[(i * (i - 1)) / 2 + j]
              : (j > i) ? 0.f
                        : 1.f;
        }
        v8[e] = (short)f2bf(f);
    }
    *((short8v*)(ws + (mat ? L_OFF : U_OFF)) + fidx) = v8;

    if (tid < D) {
        const float dg = softplus_f(ud[tid]) + EPS;
        ((float*)(ws + LD_OFF))[tid] = logf(dg);
    }
}

// Main: per block 16 rows. GEMM1 Y1 = Xm*U^T ; mask ; GEMM2 Y2 = Y1m*L^T ; epilogue.
__global__ __launch_bounds__(512, 2)
void lu_mfma_kernel(const float* __restrict__ x,
                    const int*   __restrict__ mask,
                    const float* __restrict__ bias,
                    const char*  __restrict__ ws,
                    float* __restrict__ out_y,
                    float* __restrict__ out_logdet,
                    float* __restrict__ out_mask)
{
    __shared__ u16   xm_lds[16 * 128];   // swizzled bf16 A-tile; reused for Y1m
    __shared__ float x_lds[16 * 132];    // f32 x copy (padded stride 132: bank rotation)
    __shared__ u16   m_lds[16 * 132];    // mask flags

    const int t    = threadIdx.x;
    const int w    = t >> 6;             // wave 0..7 -> col tile
    const int l    = t & 63;
    const int row0 = blockIdx.x * 16;

    // ---- issue the long-pole HBM loads FIRST (x, mask ~900cyc) ----
    const int srow = t >> 5;             // 0..15
    const int c0   = (t & 31) * 4;
    const float4 xv = *(const float4*)(x    + (size_t)(row0 + srow) * D + c0);
    const int4   mv = *(const int4*)  (mask + (size_t)(row0 + srow) * D + c0);

    // ---- B-operand fragments from ws (L2-hot, shorter latency) ----
    const int ccol = 16 * w + (l & 15);  // this lane's output feature index
    const float bv = bias[ccol];
    short8v ufrag[4], lfrag[4];
    #pragma unroll
    for (int s = 0; s < 4; ++s) {
        const int fidx = (w * 4 + s) * 64 + l;
        ufrag[s] = *((const short8v*)(ws + U_OFF) + fidx);
        lfrag[s] = *((const short8v*)(ws + L_OFF) + fidx);
    }
    const float4 ldg = *(const float4*)((const float*)(ws + LD_OFF) + c0);

    // ---- stage x/mask (16 rows x 128), out_mask, logdet ----
    *(float4*)(out_mask + (size_t)(row0 + srow) * D + c0) =
        make_float4((float)mv.x, (float)mv.y, (float)mv.z, (float)mv.w);

    *(float4*)&x_lds[srow * 132 + c0] = xv;
    u16x4 mq; mq[0]=(u16)mv.x; mq[1]=(u16)mv.y; mq[2]=(u16)mv.z; mq[3]=(u16)mv.w;
    *(u16x4*)&m_lds[srow * 132 + c0] = mq;

    u16x4 xb;
    xb[0] = f2bf(mv.x ? xv.x : 0.f);
    xb[1] = f2bf(mv.y ? xv.y : 0.f);
    xb[2] = f2bf(mv.z ? xv.z : 0.f);
    xb[3] = f2bf(mv.w ? xv.w : 0.f);
    const int xi = (srow * 128 + c0) ^ ((srow & 7) << 3);
    *(u16x4*)&xm_lds[xi] = xb;

    float part = (mv.x ? ldg.x : 0.f) + (mv.y ? ldg.y : 0.f) +
                 (mv.z ? ldg.z : 0.f) + (mv.w ? ldg.w : 0.f);
    #pragma unroll
    for (int sh = 16; sh > 0; sh >>= 1) part += __shfl_xor(part, sh, 64);
    if ((t & 31) == 0) out_logdet[row0 + srow] = part;

    __syncthreads();

    // ---- GEMM1: acc = Xm * U^T  (A: row=l&15, k=(l>>4)*8+e+32s) ----
    const int arow = l & 15;
    const int ablk = (l >> 4) * 8;
    f32x4 acc = {0.f, 0.f, 0.f, 0.f};
    #pragma unroll
    for (int s = 0; s < 4; ++s) {
        const int ai = (arow * 128 + s * 32 + ablk) ^ ((arow & 7) << 3);
        const short8v a = *(const short8v*)&xm_lds[ai];
        acc = __builtin_amdgcn_mfma_f32_16x16x32_bf16(a, ufrag[s], acc, 0, 0, 0);
    }

    __syncthreads();   // all A1 reads complete before overwrite

    // ---- mask C1, write Y1m (bf16, swizzled) back into xm_lds ----
    #pragma unroll
    for (int p = 0; p < 4; ++p) {
        const int r = (l >> 4) * 4 + p;
        const u16 m = m_lds[r * 132 + ccol];
        const float v = m ? acc[p] : 0.f;
        const int yi = (r * 128 + ccol) ^ ((r & 7) << 3);
        xm_lds[yi] = f2bf(v);
    }

    __syncthreads();

    // ---- GEMM2: acc2 = Y1m * L^T ----
    f32x4 acc2 = {0.f, 0.f, 0.f, 0.f};
    #pragma unroll
    for (int s = 0; s < 4; ++s) {
        const int ai = (arow * 128 + s * 32 + ablk) ^ ((arow & 7) << 3);
        const short8v a = *(const short8v*)&xm_lds[ai];
        acc2 = __builtin_amdgcn_mfma_f32_16x16x32_bf16(a, lfrag[s], acc2, 0, 0, 0);
    }

    // ---- epilogue: y = m ? (acc2 + bias) : x ----
    #pragma unroll
    for (int p = 0; p < 4; ++p) {
        const int r = (l >> 4) * 4 + p;
        const u16 m = m_lds[r * 132 + ccol];
        const float yv = m ? (acc2[p] + bv) : x_lds[r * 132 + ccol];
        out_y[(size_t)(row0 + r) * D + ccol] = yv;
    }
}

extern "C" void kernel_launch(void* const* d_in, const int* in_sizes, int n_in,
                              void* d_out, int out_size, void* d_ws, size_t ws_size,
                              hipStream_t stream) {
    const float* x     = (const float*)d_in[0];
    const int*   mask  = (const int*)d_in[1];
    const float* low_e = (const float*)d_in[2];
    const float* up_e  = (const float*)d_in[3];
    const float* ud    = (const float*)d_in[4];
    const float* bias  = (const float*)d_in[5];

    const int n_rows = in_sizes[0] / D;                // 8192
    float* out_y      = (float*)d_out;
    float* out_logdet = out_y + (size_t)n_rows * D;
    float* out_mask   = out_logdet + n_rows;

    char* ws = (char*)d_ws;

    lu_setup_kernel<<<16, 256, 0, stream>>>(low_e, up_e, ud, ws);
    lu_mfma_kernel<<<n_rows / 16, 512, 0, stream>>>(
        x, mask, bias, ws, out_y, out_logdet, out_mask);
}